// Round 7
// baseline (118.606 us; speedup 1.0000x reference)
//
#include <hip/hip_runtime.h>

// Self-attention (SAGAN-style): B=8, C=64, H=W=64 -> N=4096, E=C/8=8.
// Round 18: halve per-CU K/V return AT PRESERVED OCCUPANCY. r17's XCD
// swizzle regressed (-3.4us): whole 2MB workspace fits in ONE XCD L2, so
// swizzle had no L2 upside -- mapping reverted. Model: attn memory side is
// L1<->RF return BW/latency (r14 +2.3us on return dedup; r15 neutral only
// because 4-tile came with halved occupancy). This round: 512-thr blocks
// (8 waves), 64 q (4 tiles), split-K 8 (wave = 512 keys = 8 chunks of 64),
// grid 512 = 2 blocks/CU = 16 waves/CU = 4 waves/SIMD (IDENTICAL to r14)
// while each K/V load feeds 4 tiles (was 2) -> per-CU return 768->384KB.
// Masked-Q frags built per-MFMA as transient selects (quad==g ? qt : 0):
// +64 VALU/chunk, but r13 proved VALU slack; keeps VGPR under the
// launch_bounds(512,4) 128-cap (no spill; occupancy guaranteed). Combine:
// all 8 waves write OB, waves 0-3 each reduce one tile (8 partials).
// Epilogue = r15's verified 64-px form over 512 threads (VL stride 13).
// Predicted: attn -1.5..-3us -> total ~103.5-105 if return-bound; neutral
// => latency-structure-bound, r16 champion, practical roofline near.
// Kept: r16 wave-shared qkv (proj = wave id, -0.7us), fexp2 Schraudolph
// (absmax 0.0098), panel V [b][128][16][32] with ones-row 8 (l = sum(p)
// on the MFMA pipe), in-register P via permuted key map (verified
// r6-r17), full-wave dedup'd K loads (r14), depth-2 register prefetch,
// v_perm pack, fused Wo/residual epilogue.
// Non-attn ~84us is fixed harness overhead (0xAA re-poison fills at ~80%
// of HBM peak); the two kernels are the only lever.

#define BB   8
#define CC   64
#define NPIX 4096
#define EE   8
#define BN   (BB*NPIX)        // 32768
#define YSZ  (BB*CC*NPIX)     // 2097152
#define LOG2E 1.4426950408889634f

typedef __attribute__((ext_vector_type(8))) short bf16x8;
typedef __attribute__((ext_vector_type(4))) float f32x4;

__device__ __forceinline__ unsigned short f2bf_rne(float x) {
    unsigned u = __float_as_uint(x);
    u += 0x7FFFu + ((u >> 16) & 1u);
    return (unsigned short)(u >> 16);
}
// dst = [hi16(a), hi16(b)] in one v_perm_b32 (truncation; bias cancels in
// the softmax normalize since l sums the same truncated p via the ones-row).
__device__ __forceinline__ unsigned pack_bf_trunc(float a, float b) {
    return __builtin_amdgcn_perm(__float_as_uint(b), __float_as_uint(a),
                                 0x07060302u);
}
// Schraudolph exp2: piecewise-linear mantissa, error-centered magic.
// (127 - 0.0347) * 2^23 = 1065062131; max relative err ~ +-3.5%, zero-mean.
// 2 full-rate VALU ops vs quarter-rate v_exp_f32.
__device__ __forceinline__ float fexp2(float x) {
    return __int_as_float((int)fmaf(x, 8388608.f, 1065062131.f));
}
// Force a (wave-uniform) pointer into SGPRs so dependent loads are s_loads.
__device__ __forceinline__ const float* rfl_ptr(const float* p) {
    unsigned long long u = (unsigned long long)p;
    unsigned lo = __builtin_amdgcn_readfirstlane((unsigned)u);
    unsigned hi = __builtin_amdgcn_readfirstlane((unsigned)(u >> 32));
    return (const float*)(((unsigned long long)hi << 32) | lo);
}

// ---- K1: QKV projection, proj = wave id; 3 waves share one x-slice ----
// Block = 192 thr = 3 waves over the SAME 64 pixels -> x fetched from HBM
// once, waves 1-2 hit L1/L2. Per-wave body identical to r13's per-block.
__global__ __launch_bounds__(192) void qkv_kernel(
    const float* __restrict__ x,
    const float* __restrict__ Wk, const float* __restrict__ bk,
    const float* __restrict__ Wq, const float* __restrict__ bq,
    const float* __restrict__ Wv, const float* __restrict__ bv,
    unsigned short* __restrict__ QT, unsigned short* __restrict__ KT,
    unsigned short* __restrict__ VT)
{
    const int proj = threadIdx.x >> 6;   // wave id: 0=Q, 1=K, 2=V
    const int lane = threadIdx.x & 63;
    const float* W    = rfl_ptr((proj == 0) ? Wq : (proj == 1) ? Wk : Wv);
    const float* bias = rfl_ptr((proj == 0) ? bq : (proj == 1) ? bk : bv);

    const int bm = blockIdx.x*64 + lane;
    const int b  = bm >> 12;
    const int n  = bm & (NPIX-1);
    const float* xb = x + (size_t)b*CC*NPIX + n;

    float xv[CC];
    #pragma unroll
    for (int c = 0; c < CC; ++c) xv[c] = xb[(size_t)c*NPIX];

    float f[EE];
    #pragma unroll
    for (int e = 0; e < EE; ++e) {
        float acc = bias[e];
        #pragma unroll
        for (int c = 0; c < CC; ++c) acc = fmaf(W[e*CC+c], xv[c], acc);
        f[e] = acc;
    }

    if (proj == 0) {
        union { unsigned short s[8]; uint4 v; } t;
        #pragma unroll
        for (int e = 0; e < EE; ++e) t.s[e] = f2bf_rne(f[e] * LOG2E);
        *(uint4*)(QT + (size_t)bm*EE) = t.v;
    } else if (proj == 1) {
        union { unsigned short s[8]; uint4 v; } t;
        #pragma unroll
        for (int e = 0; e < EE; ++e) t.s[e] = f2bf_rne(f[e]);
        *(uint4*)(KT + (size_t)bm*EE) = t.v;
    } else {
        // panel p = n>>5; within-row short offset for key c = n&31:
        // quad q(c) block of 8: [0..3]=keys 4q..4q+3, [4..7]=keys 16+4q..+3
        const int p   = n >> 5;
        const int c   = n & 31;
        const int off = ((c & 15) >> 2)*8 + ((c >> 4) << 2) + (c & 3);
        unsigned short* vp = VT + ((size_t)(b*128 + p)*16)*32 + off;
        #pragma unroll
        for (int e = 0; e < EE; ++e) vp[e*32] = f2bf_rne(f[e]);
        vp[8*32] = 0x3F80;                         // ones row -> l via GEMM2
    }
}

// ---- K2: flash attention, 8 waves x 4 q-tiles, split-K 8 ----
// Block = 64 queries, 512 threads; grid = 8*64 = 512 = 2 blocks/CU.
__global__ __launch_bounds__(512, 4) void attn_fused(
    const unsigned short* __restrict__ QT, const unsigned short* __restrict__ KT,
    const unsigned short* __restrict__ VT,
    const float* __restrict__ x, const float* __restrict__ Wo,
    const float* __restrict__ bo, const float* __restrict__ gamma,
    float* __restrict__ out)
{
    __shared__ float OB[8*4*256];  // 8 waves x 4 tiles x 64 lanes x f32x4 = 32KB
    __shared__ float VL[64*13];    // normalized v per pixel (stride 13)
    __shared__ float Wos[CC*9];    // stride 9: conflict-free epilogue reads
    __shared__ float bos[CC];

    const int tid  = threadIdx.x;
    const int wave = tid >> 6, lane = tid & 63;
    const int quad = lane >> 4, lm = lane & 15;
    const int b  = blockIdx.x >> 6;
    const int m0 = (blockIdx.x & 63) * 64;

    for (int i = tid; i < CC*EE; i += 512) Wos[(i>>3)*9 + (i&7)] = Wo[i];
    if (tid < CC) bos[tid] = bo[tid];

    // Q tiles (one-time quad-replicated loads; only lm-row matters).
    // Masked fragments are built TRANSIENTLY at each MFMA: (quad==g)?qt:0
    // selects keys 16g..16g+15 of the 64-key kf load (B zero elsewhere).
    // S output reg map: key = 16g + 4*quad + r, query col = m0 + 16t + lm.
    const bf16x8 kz = {0,0,0,0,0,0,0,0};
    bf16x8 qt[4];
    #pragma unroll
    for (int t = 0; t < 4; ++t)
        qt[t] = *(const bf16x8*)(QT + (size_t)(b*NPIX + m0 + 16*t + lm)*EE);

    f32x4 oacc[4];
    #pragma unroll
    for (int t = 0; t < 4; ++t) oacc[t] = (f32x4){0.f,0.f,0.f,0.f};
    const f32x4 zc = {0.f,0.f,0.f,0.f};

    const unsigned short* Kb = KT + (size_t)b*NPIX*EE;
    const int n_start = wave*512;                  // split-K 8: 512 keys/wave
    // Full-wave K load: lane l -> key n_start + l (1KB coalesced, 0 waste).
    const unsigned short* kl = Kb + (size_t)(n_start + lane)*EE;
    // V panel: row clamp (rows 9..15 -> 8; same lines, C rows 9..15 discarded)
    const int lmv = (lm < 9) ? lm : 8;
    const unsigned short* vl = VT + ((size_t)(b*128 + (n_start >> 5))*16 + lmv)*32
                                  + quad*8;

    // 2-deep register pipeline over 8 chunks of 64 keys
    bf16x8 kfa  = *(const bf16x8*)(kl);
    bf16x8 vf0a = *(const bf16x8*)(vl);
    bf16x8 vf1a = *(const bf16x8*)(vl + 512);
    bf16x8 kfb  = *(const bf16x8*)(kl + 64*EE);
    bf16x8 vf0b = *(const bf16x8*)(vl + 1024);
    bf16x8 vf1b = *(const bf16x8*)(vl + 1536);
    kl += 128*EE; vl += 2048;

    #pragma unroll 2
    for (int ch = 0; ch < 8; ++ch) {
        bf16x8 kf = kfa, vf0 = vf0a, vf1 = vf1a;
        kfa = kfb; vf0a = vf0b; vf1a = vf1b;       // ping-pong, no movs
        if (ch < 6) {                              // prefetch chunk ch+2
            kfb  = *(const bf16x8*)(kl);
            vf0b = *(const bf16x8*)(vl);
            vf1b = *(const bf16x8*)(vl + 512);
            kl += 64*EE; vl += 1024;
        }

        #pragma unroll
        for (int t = 0; t < 4; ++t) {
            // s_g reg r = S[key 16g + 4*quad + r][query m0 + 16t + lm]
            f32x4 s0 = __builtin_amdgcn_mfma_f32_16x16x32_bf16(
                           kf, (quad == 0) ? qt[t] : kz, zc, 0, 0, 0);
            f32x4 s1 = __builtin_amdgcn_mfma_f32_16x16x32_bf16(
                           kf, (quad == 1) ? qt[t] : kz, zc, 0, 0, 0);
            f32x4 s2 = __builtin_amdgcn_mfma_f32_16x16x32_bf16(
                           kf, (quad == 2) ? qt[t] : kz, zc, 0, 0, 0);
            f32x4 s3 = __builtin_amdgcn_mfma_f32_16x16x32_bf16(
                           kf, (quad == 3) ? qt[t] : kz, zc, 0, 0, 0);

            float a0 = fexp2(s0.x), a1 = fexp2(s0.y);
            float a2 = fexp2(s0.z), a3 = fexp2(s0.w);
            float a4 = fexp2(s1.x), a5 = fexp2(s1.y);
            float a6 = fexp2(s1.z), a7 = fexp2(s1.w);
            float c0 = fexp2(s2.x), c1 = fexp2(s2.y);
            float c2 = fexp2(s2.z), c3 = fexp2(s2.w);
            float c4 = fexp2(s3.x), c5 = fexp2(s3.y);
            float c6 = fexp2(s3.z), c7 = fexp2(s3.w);

            // B2 fragment IS the C-layout regs under the permuted key map
            // (slot k=quad*8+j -> key quad*4+j (j<4) / 16+quad*4+(j-4)),
            // matching the V panel row layout. Verified r6-r17.
            union { unsigned u[4]; bf16x8 v; } p0, p1;
            p0.u[0] = pack_bf_trunc(a0, a1); p0.u[1] = pack_bf_trunc(a2, a3);
            p0.u[2] = pack_bf_trunc(a4, a5); p0.u[3] = pack_bf_trunc(a6, a7);
            p1.u[0] = pack_bf_trunc(c0, c1); p1.u[1] = pack_bf_trunc(c2, c3);
            p1.u[2] = pack_bf_trunc(c4, c5); p1.u[3] = pack_bf_trunc(c6, c7);
            oacc[t] = __builtin_amdgcn_mfma_f32_16x16x32_bf16(vf0, p0.v, oacc[t], 0, 0, 0);
            oacc[t] = __builtin_amdgcn_mfma_f32_16x16x32_bf16(vf1, p1.v, oacc[t], 0, 0, 0);
        }
    }

    // cross-wave combine: all 8 waves dump partials; waves 0-3 reduce one
    // tile each. l rides along in C-row 8 (quad2 lanes, reg .x).
    #pragma unroll
    for (int t = 0; t < 4; ++t)
        *(f32x4*)(OB + ((size_t)wave*4 + t)*256 + lane*4) = oacc[t];
    __syncthreads();
    if (wave < 4) {
        const int t = wave;
        f32x4 oT = {0.f,0.f,0.f,0.f};
        #pragma unroll
        for (int w = 0; w < 8; ++w)
            oT += *(f32x4*)(OB + ((size_t)w*4 + t)*256 + lane*4);
        float lT  = __shfl(oT.x, 32 + lm);         // row 8 = sum of trunc(p)
        float inv = 1.f / lT;
        if (quad < 2) {                            // rows e = quad*4+reg in 0..7
            f32x4 sT = { oT.x*inv, oT.y*inv, oT.z*inv, oT.w*inv };
            *(f32x4*)(VL + (16*t + lm)*13 + quad*4) = sT;
        }
    }
    __syncthreads();

    // Fused epilogue: 64 px x 64 ch over 512 threads (8 ch each).
    const float g  = gamma[0];
    const int   px = tid & 63;
    const int   cg = tid >> 6;                     // 0..7
    const size_t base = (size_t)b*CC*NPIX + (m0 + px);
    float v[EE];
    #pragma unroll
    for (int e = 0; e < EE; ++e) v[e] = VL[px*13 + e];
    #pragma unroll
    for (int i = 0; i < 8; ++i) {
        const int c = cg*8 + i;
        float o = bos[c];
        #pragma unroll
        for (int e = 0; e < EE; ++e) o += Wos[c*9 + e] * v[e];
        out[(size_t)YSZ + base + (size_t)c*NPIX] = o;
        out[base + (size_t)c*NPIX] = g*o + x[base + (size_t)c*NPIX];
    }
    if (blockIdx.x == 0 && tid == 0) out[2*(size_t)YSZ] = g;  // gamma passthrough
}

extern "C" void kernel_launch(void* const* d_in, const int* in_sizes, int n_in,
                              void* d_out, int out_size, void* d_ws, size_t ws_size,
                              hipStream_t stream) {
    const float* x     = (const float*)d_in[0];
    const float* Wk    = (const float*)d_in[1];
    const float* bk    = (const float*)d_in[2];
    const float* Wq    = (const float*)d_in[3];
    const float* bq    = (const float*)d_in[4];
    const float* Wv    = (const float*)d_in[5];
    const float* bv    = (const float*)d_in[6];
    const float* Wo    = (const float*)d_in[7];
    const float* bo    = (const float*)d_in[8];
    const float* gamma = (const float*)d_in[9];
    float* out = (float*)d_out;

    // ws: QT(512KB) | KT(512KB) | VT(1MB bf16, panelized [b][128][16][32];
    // row 8 = ones, rows 9..15 poison -> only discarded C rows) = 2MB
    unsigned short* QT = (unsigned short*)d_ws;
    unsigned short* KT = QT + (size_t)BN*EE;
    unsigned short* VT = KT + (size_t)BN*EE;

    qkv_kernel<<<BN/64, 192, 0, stream>>>(x, Wk, bk, Wq, bq, Wv, bv, QT, KT, VT);
    attn_fused<<<BB*64, 512, 0, stream>>>(QT, KT, VT, x, Wo, bo, gamma, out);
}

// Round 8
// 106.460 us; speedup vs baseline: 1.1141x; 1.1141x over previous
//
#include <hip/hip_runtime.h>

// Self-attention (SAGAN-style): B=8, C=64, H=W=64 -> N=4096, E=C/8=8.
// Round 19: consolidation on the r16 champion (106.6us) + two low-risk
// micro-levers. r18's 4-tile retry regressed (118.6): transient masked-Q
// selects = 16 cndmask-x4 per chunk, VALU doubled + ping-pong broken. The
// 4-tile axis is closed (r15, r18 both failed); post-r14 attn is a
// latency/issue equilibrium where the r14/r16 structure is the local
// optimum. r17 taught: block mapping must keep consecutive blocks on
// consecutive m0 within one b (output-write locality) -- r16 already does.
// This round, on byte-identical r16 base:
// (1) s_setprio(1) around the per-chunk MFMA+exp cluster (T5: +4-7% on
//     attn-style free-running waves; our 4 waves are barrier-free for the
//     16-chunk sweep across 16 waves/CU -> role diversity exists).
// (2) parallel combine: all 4 waves dump partials, waves 0/1 reduce tiles
//     A/B concurrently (was wave0 serial both) -> shorter serial tail.
// Predicted ~105-106us; if neutral vs 106.6, declare roofline next round.
// Kept: wave-shared qkv (proj = wave id, x HBM-fetched once), fexp2
// Schraudolph (absmax 0.0098), panel V [b][128][16][32] with ones-row 8
// (l = sum(p) on the MFMA pipe), in-register P via permuted key map
// (verified r6-r18), full-wave dedup'd K loads + prebuilt masked Q frags
// (r14, -2.3us), 2 q-tiles/wave, depth-2 register prefetch, v_perm pack,
// fused Wo/residual epilogue, split-K 4 waves.
// Non-attn ~84us is fixed harness overhead (0xAA re-poison fills at ~80%
// of HBM peak); the two kernels are the only lever.

#define BB   8
#define CC   64
#define NPIX 4096
#define EE   8
#define BN   (BB*NPIX)        // 32768
#define YSZ  (BB*CC*NPIX)     // 2097152
#define LOG2E 1.4426950408889634f

typedef __attribute__((ext_vector_type(8))) short bf16x8;
typedef __attribute__((ext_vector_type(4))) float f32x4;

__device__ __forceinline__ unsigned short f2bf_rne(float x) {
    unsigned u = __float_as_uint(x);
    u += 0x7FFFu + ((u >> 16) & 1u);
    return (unsigned short)(u >> 16);
}
// dst = [hi16(a), hi16(b)] in one v_perm_b32 (truncation; bias cancels in
// the softmax normalize since l sums the same truncated p via the ones-row).
__device__ __forceinline__ unsigned pack_bf_trunc(float a, float b) {
    return __builtin_amdgcn_perm(__float_as_uint(b), __float_as_uint(a),
                                 0x07060302u);
}
// Schraudolph exp2: piecewise-linear mantissa, error-centered magic.
// (127 - 0.0347) * 2^23 = 1065062131; max relative err ~ +-3.5%, zero-mean.
// 2 full-rate VALU ops vs quarter-rate v_exp_f32.
__device__ __forceinline__ float fexp2(float x) {
    return __int_as_float((int)fmaf(x, 8388608.f, 1065062131.f));
}
// Force a (wave-uniform) pointer into SGPRs so dependent loads are s_loads.
__device__ __forceinline__ const float* rfl_ptr(const float* p) {
    unsigned long long u = (unsigned long long)p;
    unsigned lo = __builtin_amdgcn_readfirstlane((unsigned)u);
    unsigned hi = __builtin_amdgcn_readfirstlane((unsigned)(u >> 32));
    return (const float*)(((unsigned long long)hi << 32) | lo);
}

// ---- K1: QKV projection, proj = wave id; 3 waves share one x-slice ----
// Block = 192 thr = 3 waves over the SAME 64 pixels -> x fetched from HBM
// once, waves 1-2 hit L1/L2. Per-wave body identical to r13's per-block.
__global__ __launch_bounds__(192) void qkv_kernel(
    const float* __restrict__ x,
    const float* __restrict__ Wk, const float* __restrict__ bk,
    const float* __restrict__ Wq, const float* __restrict__ bq,
    const float* __restrict__ Wv, const float* __restrict__ bv,
    unsigned short* __restrict__ QT, unsigned short* __restrict__ KT,
    unsigned short* __restrict__ VT)
{
    const int proj = threadIdx.x >> 6;   // wave id: 0=Q, 1=K, 2=V
    const int lane = threadIdx.x & 63;
    const float* W    = rfl_ptr((proj == 0) ? Wq : (proj == 1) ? Wk : Wv);
    const float* bias = rfl_ptr((proj == 0) ? bq : (proj == 1) ? bk : bv);

    const int bm = blockIdx.x*64 + lane;
    const int b  = bm >> 12;
    const int n  = bm & (NPIX-1);
    const float* xb = x + (size_t)b*CC*NPIX + n;

    float xv[CC];
    #pragma unroll
    for (int c = 0; c < CC; ++c) xv[c] = xb[(size_t)c*NPIX];

    float f[EE];
    #pragma unroll
    for (int e = 0; e < EE; ++e) {
        float acc = bias[e];
        #pragma unroll
        for (int c = 0; c < CC; ++c) acc = fmaf(W[e*CC+c], xv[c], acc);
        f[e] = acc;
    }

    if (proj == 0) {
        union { unsigned short s[8]; uint4 v; } t;
        #pragma unroll
        for (int e = 0; e < EE; ++e) t.s[e] = f2bf_rne(f[e] * LOG2E);
        *(uint4*)(QT + (size_t)bm*EE) = t.v;
    } else if (proj == 1) {
        union { unsigned short s[8]; uint4 v; } t;
        #pragma unroll
        for (int e = 0; e < EE; ++e) t.s[e] = f2bf_rne(f[e]);
        *(uint4*)(KT + (size_t)bm*EE) = t.v;
    } else {
        // panel p = n>>5; within-row short offset for key c = n&31:
        // quad q(c) block of 8: [0..3]=keys 4q..4q+3, [4..7]=keys 16+4q..+3
        const int p   = n >> 5;
        const int c   = n & 31;
        const int off = ((c & 15) >> 2)*8 + ((c >> 4) << 2) + (c & 3);
        unsigned short* vp = VT + ((size_t)(b*128 + p)*16)*32 + off;
        #pragma unroll
        for (int e = 0; e < EE; ++e) vp[e*32] = f2bf_rne(f[e]);
        vp[8*32] = 0x3F80;                         // ones row -> l via GEMM2
    }
}

// ---- K2: flash attention, 64-key chunks, dedup'd K loads (r14 form) ----
// Block = 32 queries; 4 waves split the 4096 keys x4. Grid = 8*128 = 1024.
__global__ __launch_bounds__(256, 4) void attn_fused(
    const unsigned short* __restrict__ QT, const unsigned short* __restrict__ KT,
    const unsigned short* __restrict__ VT,
    const float* __restrict__ x, const float* __restrict__ Wo,
    const float* __restrict__ bo, const float* __restrict__ gamma,
    float* __restrict__ out)
{
    __shared__ float OB[4*2*256];  // 4 waves x {A,B} x 64 lanes x f32x4 = 8KB
    __shared__ float VL[32*12];    // normalized v per pixel
    __shared__ float Wos[CC*9];    // stride 9: conflict-free epilogue reads
    __shared__ float bos[CC];

    const int tid  = threadIdx.x;
    const int wave = tid >> 6, lane = tid & 63;
    const int quad = lane >> 4, lm = lane & 15;
    const int b  = blockIdx.x >> 7;
    const int m0 = (blockIdx.x & 127) * 32;

    for (int i = tid; i < CC*EE; i += 256) Wos[(i>>3)*9 + (i&7)] = Wo[i];
    if (tid < CC) bos[tid] = bo[tid];

    // Q fragments per key-group g: Q rows in quad-g lanes, zeros elsewhere.
    // Group-g S-MFMA mfma(kf, q[g]) reads A only from quad-g lanes (B zero
    // in other k-slots) = keys 16g..16g+15 of the 64-key kf load.
    const bf16x8 kz = {0,0,0,0,0,0,0,0};
    bf16x8 qtA = *(const bf16x8*)(QT + (size_t)(b*NPIX + m0 + lm)*EE);
    bf16x8 qtB = *(const bf16x8*)(QT + (size_t)(b*NPIX + m0 + 16 + lm)*EE);
    bf16x8 qA[4], qB[4];
    #pragma unroll
    for (int g = 0; g < 4; ++g) {
        qA[g] = (quad == g) ? qtA : kz;
        qB[g] = (quad == g) ? qtB : kz;
    }

    f32x4 oaccA = {0.f,0.f,0.f,0.f}, oaccB = {0.f,0.f,0.f,0.f};
    const f32x4 zc = {0.f,0.f,0.f,0.f};

    const unsigned short* Kb = KT + (size_t)b*NPIX*EE;
    const int n_start = wave*1024;                 // split-K: 1024 keys/wave
    // Full-wave K load: lane l -> key n_start + l (1KB coalesced, 0 waste).
    const unsigned short* kl = Kb + (size_t)(n_start + lane)*EE;
    // V panel: row clamp (rows 9..15 -> 8; same lines, C rows 9..15 discarded)
    const int lmv = (lm < 9) ? lm : 8;
    const unsigned short* vl = VT + ((size_t)(b*128 + (n_start >> 5))*16 + lmv)*32
                                  + quad*8;

    // 2-deep register pipeline over 16 chunks of 64 keys
    bf16x8 kfa  = *(const bf16x8*)(kl);
    bf16x8 vf0a = *(const bf16x8*)(vl);
    bf16x8 vf1a = *(const bf16x8*)(vl + 512);
    bf16x8 kfb  = *(const bf16x8*)(kl + 64*EE);
    bf16x8 vf0b = *(const bf16x8*)(vl + 1024);
    bf16x8 vf1b = *(const bf16x8*)(vl + 1536);
    kl += 128*EE; vl += 2048;

    #pragma unroll 2
    for (int ch = 0; ch < 16; ++ch) {
        bf16x8 kf = kfa, vf0 = vf0a, vf1 = vf1a;
        kfa = kfb; vf0a = vf0b; vf1a = vf1b;       // ping-pong, no movs
        if (ch < 14) {                             // prefetch chunk ch+2
            kfb  = *(const bf16x8*)(kl);
            vf0b = *(const bf16x8*)(vl);
            vf1b = *(const bf16x8*)(vl + 512);
            kl += 64*EE; vl += 1024;
        }

        // T5: favor this wave while it's in its MFMA+exp cluster; waves in
        // their load-issue phase run at prio 0 -> scheduler feeds the
        // matrix/trans pipes first. (Structure-conditional win: free-
        // running waves, no intra-loop barriers.)
        __builtin_amdgcn_s_setprio(1);

        // ---- tile A ----
        // s_g reg r = S[key 16g + 4*quad + r][query m0+lm]
        f32x4 s0a = __builtin_amdgcn_mfma_f32_16x16x32_bf16(kf, qA[0], zc, 0, 0, 0);
        f32x4 s1a = __builtin_amdgcn_mfma_f32_16x16x32_bf16(kf, qA[1], zc, 0, 0, 0);
        f32x4 s2a = __builtin_amdgcn_mfma_f32_16x16x32_bf16(kf, qA[2], zc, 0, 0, 0);
        f32x4 s3a = __builtin_amdgcn_mfma_f32_16x16x32_bf16(kf, qA[3], zc, 0, 0, 0);
        {
            float a0 = fexp2(s0a.x), a1 = fexp2(s0a.y);
            float a2 = fexp2(s0a.z), a3 = fexp2(s0a.w);
            float a4 = fexp2(s1a.x), a5 = fexp2(s1a.y);
            float a6 = fexp2(s1a.z), a7 = fexp2(s1a.w);
            float c0 = fexp2(s2a.x), c1 = fexp2(s2a.y);
            float c2 = fexp2(s2a.z), c3 = fexp2(s2a.w);
            float c4 = fexp2(s3a.x), c5 = fexp2(s3a.y);
            float c6 = fexp2(s3a.z), c7 = fexp2(s3a.w);
            // B2 fragment IS the C-layout regs under the permuted key map
            // (slot k=quad*8+j -> key quad*4+j (j<4) / 16+quad*4+(j-4)),
            // matching the V panel row layout. Verified r6-r18.
            union { unsigned u[4]; bf16x8 v; } p0, p1;
            p0.u[0] = pack_bf_trunc(a0, a1); p0.u[1] = pack_bf_trunc(a2, a3);
            p0.u[2] = pack_bf_trunc(a4, a5); p0.u[3] = pack_bf_trunc(a6, a7);
            p1.u[0] = pack_bf_trunc(c0, c1); p1.u[1] = pack_bf_trunc(c2, c3);
            p1.u[2] = pack_bf_trunc(c4, c5); p1.u[3] = pack_bf_trunc(c6, c7);
            oaccA = __builtin_amdgcn_mfma_f32_16x16x32_bf16(vf0, p0.v, oaccA, 0, 0, 0);
            oaccA = __builtin_amdgcn_mfma_f32_16x16x32_bf16(vf1, p1.v, oaccA, 0, 0, 0);
        }
        // ---- tile B ----
        f32x4 s0b = __builtin_amdgcn_mfma_f32_16x16x32_bf16(kf, qB[0], zc, 0, 0, 0);
        f32x4 s1b = __builtin_amdgcn_mfma_f32_16x16x32_bf16(kf, qB[1], zc, 0, 0, 0);
        f32x4 s2b = __builtin_amdgcn_mfma_f32_16x16x32_bf16(kf, qB[2], zc, 0, 0, 0);
        f32x4 s3b = __builtin_amdgcn_mfma_f32_16x16x32_bf16(kf, qB[3], zc, 0, 0, 0);
        {
            float a0 = fexp2(s0b.x), a1 = fexp2(s0b.y);
            float a2 = fexp2(s0b.z), a3 = fexp2(s0b.w);
            float a4 = fexp2(s1b.x), a5 = fexp2(s1b.y);
            float a6 = fexp2(s1b.z), a7 = fexp2(s1b.w);
            float c0 = fexp2(s2b.x), c1 = fexp2(s2b.y);
            float c2 = fexp2(s2b.z), c3 = fexp2(s2b.w);
            float c4 = fexp2(s3b.x), c5 = fexp2(s3b.y);
            float c6 = fexp2(s3b.z), c7 = fexp2(s3b.w);
            union { unsigned u[4]; bf16x8 v; } p0, p1;
            p0.u[0] = pack_bf_trunc(a0, a1); p0.u[1] = pack_bf_trunc(a2, a3);
            p0.u[2] = pack_bf_trunc(a4, a5); p0.u[3] = pack_bf_trunc(a6, a7);
            p1.u[0] = pack_bf_trunc(c0, c1); p1.u[1] = pack_bf_trunc(c2, c3);
            p1.u[2] = pack_bf_trunc(c4, c5); p1.u[3] = pack_bf_trunc(c6, c7);
            oaccB = __builtin_amdgcn_mfma_f32_16x16x32_bf16(vf0, p0.v, oaccB, 0, 0, 0);
            oaccB = __builtin_amdgcn_mfma_f32_16x16x32_bf16(vf1, p1.v, oaccB, 0, 0, 0);
        }
        __builtin_amdgcn_s_setprio(0);
    }

    // cross-wave combine: all 4 waves dump partials; waves 0/1 reduce
    // tiles A/B in parallel. l rides along in C-row 8 (quad2, reg .x).
    *(f32x4*)(OB + ((size_t)wave*2 + 0)*256 + lane*4) = oaccA;
    *(f32x4*)(OB + ((size_t)wave*2 + 1)*256 + lane*4) = oaccB;
    __syncthreads();
    if (wave < 2) {
        const int t = wave;                        // 0 -> tile A, 1 -> tile B
        f32x4 oT = {0.f,0.f,0.f,0.f};
        #pragma unroll
        for (int w = 0; w < 4; ++w)
            oT += *(f32x4*)(OB + ((size_t)w*2 + t)*256 + lane*4);
        float lT  = __shfl(oT.x, 32 + lm);         // row 8 = sum of trunc(p)
        float inv = 1.f / lT;
        if (quad < 2) {                            // rows e = quad*4+reg in 0..7
            f32x4 sT = { oT.x*inv, oT.y*inv, oT.z*inv, oT.w*inv };
            *(f32x4*)(VL + (16*t + lm)*12 + quad*4) = sT;
        }
    }
    __syncthreads();

    // Fused epilogue: 32 px x 64 ch over 256 threads (8 ch each).
    const float g  = gamma[0];
    const int   px = tid & 31;
    const int   cg = tid >> 5;                     // 0..7
    const size_t base = (size_t)b*CC*NPIX + (m0 + px);
    float v[EE];
    #pragma unroll
    for (int e = 0; e < EE; ++e) v[e] = VL[px*12 + e];
    #pragma unroll
    for (int i = 0; i < 8; ++i) {
        const int c = cg*8 + i;
        float o = bos[c];
        #pragma unroll
        for (int e = 0; e < EE; ++e) o += Wos[c*9 + e] * v[e];
        out[(size_t)YSZ + base + (size_t)c*NPIX] = o;
        out[base + (size_t)c*NPIX] = g*o + x[base + (size_t)c*NPIX];
    }
    if (blockIdx.x == 0 && tid == 0) out[2*(size_t)YSZ] = g;  // gamma passthrough
}

extern "C" void kernel_launch(void* const* d_in, const int* in_sizes, int n_in,
                              void* d_out, int out_size, void* d_ws, size_t ws_size,
                              hipStream_t stream) {
    const float* x     = (const float*)d_in[0];
    const float* Wk    = (const float*)d_in[1];
    const float* bk    = (const float*)d_in[2];
    const float* Wq    = (const float*)d_in[3];
    const float* bq    = (const float*)d_in[4];
    const float* Wv    = (const float*)d_in[5];
    const float* bv    = (const float*)d_in[6];
    const float* Wo    = (const float*)d_in[7];
    const float* bo    = (const float*)d_in[8];
    const float* gamma = (const float*)d_in[9];
    float* out = (float*)d_out;

    // ws: QT(512KB) | KT(512KB) | VT(1MB bf16, panelized [b][128][16][32];
    // row 8 = ones, rows 9..15 poison -> only discarded C rows) = 2MB
    unsigned short* QT = (unsigned short*)d_ws;
    unsigned short* KT = QT + (size_t)BN*EE;
    unsigned short* VT = KT + (size_t)BN*EE;

    qkv_kernel<<<BN/64, 192, 0, stream>>>(x, Wk, bk, Wq, bq, Wv, bv, QT, KT, VT);
    attn_fused<<<BB*128, 256, 0, stream>>>(QT, KT, VT, x, Wo, bo, gamma, out);
}